// Round 5
// baseline (4648.335 us; speedup 1.0000x reference)
//
#include <hip/hip_runtime.h>
#include <math.h>

// Problem dims
#define B_   256
#define T_   512
#define F_   64
#define H1_  100
#define H2_  128
#define OUT_ 19
#define G1_  400   // 4*H1
#define G2_  512   // 4*H2
#define TC   64    // timesteps per chunk
#define NCHUNK (T_/TC)

// ---- LDS layout (floats) ----
// Union region [0, 32768):
//   during A0/A1: xs[TC*F_]=4096 at 0, xp1[TC*G1_]=25600 at 4096 (ends 29696)
//   during A2/B : xp2[TC*G2_]=32768 at 0
#define OFF_XS    0
#define OFF_XP1   (TC*F_)                 // 4096
#define OFF_XP2   0
#define OFF_H1C   32768                   // TC*H1_ = 6400 floats
#define OFF_ZBUF  (OFF_H1C + TC*H1_)      // 39168, 512 floats
#define OFF_H1S   (OFF_ZBUF + G2_)        // 39680, 128 floats (100 used)
#define OFF_H2S   (OFF_H1S + 128)         // 39808, 128 floats
#define LDS_FLOATS (OFF_H2S + 128)        // 39936 floats = 159744 B (<=163840)

__device__ __forceinline__ float sigm(float x) {
    return 1.0f / (1.0f + __expf(-x));
}

// Weight storage: 32 INDIVIDUALLY NAMED float4 locals (no array => no alloca
// => cannot be demoted to scratch). All indices below are literal tokens.
#define REP16(M) M(0) M(1) M(2) M(3) M(4) M(5) M(6) M(7) M(8) M(9) M(10) M(11) M(12) M(13) M(14) M(15)
#define REP25(M) REP16(M) M(16) M(17) M(18) M(19) M(20) M(21) M(22) M(23) M(24)
#define REP32(M) REP25(M) M(25) M(26) M(27) M(28) M(29) M(30) M(31)

#define DECLW(n) float4 w##n;

// load rows 4n..4n+3 of column `col` from matrix P with row stride S
#define LDW_G1(n, P) w##n = make_float4(P[(4*n+0)*G1_+j], P[(4*n+1)*G1_+j], \
                                        P[(4*n+2)*G1_+j], P[(4*n+3)*G1_+j]);
#define LDW1(n)  LDW_G1(n, W1)
#define LDU1(n)  LDW_G1(n, U1)
#define LDW_G2(n, P) w##n = make_float4(P[(4*n+0)*G2_+j], P[(4*n+1)*G2_+j], \
                                        P[(4*n+2)*G2_+j], P[(4*n+3)*G2_+j]);
#define LDW2(n)  LDW_G2(n, W2)
#define LDU2(n)  LDW_G2(n, U2)

// one float4 FMA group against base pointer held in hb4
#define DOTW(n) { float4 hv_ = hb4[n]; a0 += hv_.x*w##n.x; a1 += hv_.y*w##n.y; \
                  a2 += hv_.z*w##n.z; a3 += hv_.w*w##n.w; }

__global__ __launch_bounds__(512, 2)
void lstm_fused(
    const float* __restrict__ x,
    const float* __restrict__ W1, const float* __restrict__ U1, const float* __restrict__ b1,
    const float* __restrict__ W2, const float* __restrict__ U2, const float* __restrict__ b2,
    const float* __restrict__ Wd, const float* __restrict__ bd,
    float* __restrict__ out)
{
    __shared__ float lds[LDS_FLOATS];
    const int b = blockIdx.x;
    const int j = threadIdx.x;

    REP32(DECLW)            // w0..w31: per-phase weight column, named scalars
    float c1 = 0.0f;        // cell state, thread k<100 owns c1[k]
    float c2 = 0.0f;        // cell state, thread k<128 owns c2[k]

    if (j < 128) { lds[OFF_H1S + j] = 0.0f; lds[OFF_H2S + j] = 0.0f; }
    __syncthreads();

    const float* xrow = x + (size_t)b * T_ * F_;

    for (int ch = 0; ch < NCHUNK; ++ch) {
        // ---- stage x chunk: 4096 floats = 1024 float4, 2 per thread ----
        {
            const float4* src4 = (const float4*)(xrow + ch * TC * F_);
            float4* dst4 = (float4*)&lds[OFF_XS];
            dst4[j]       = src4[j];
            dst4[512 + j] = src4[512 + j];
        }
        // ---- load W1 column j: 16 float4 (rows 0..63) ----
        if (j < G1_) { REP16(LDW1) }
        __syncthreads();   // xs staged; prev chunk's B reads of xp2 done

        // ---- A0: xp1[t][j] = b1[j] + x_t . W1col_j  (dense, barrier-free) ----
        if (j < G1_) {
            const float bj = b1[j];
            for (int t = 0; t < TC; ++t) {
                const float4* hb4 = (const float4*)&lds[OFF_XS + t * F_];
                float a0 = bj, a1 = 0.f, a2 = 0.f, a3 = 0.f;
                REP16(DOTW)
                lds[OFF_XP1 + t * G1_ + j] = (a0 + a1) + (a2 + a3);
            }
            // swap in U1 column j: 25 float4 (rows 0..99)
            REP25(LDU1)
        }
        __syncthreads();   // xp1 complete

        // ---- A1: layer-1 recurrence over the chunk ----
        for (int t = 0; t < TC; ++t) {
            if (j < G1_) {
                const float4* hb4 = (const float4*)&lds[OFF_H1S];
                float a0 = lds[OFF_XP1 + t * G1_ + j], a1 = 0.f, a2 = 0.f, a3 = 0.f;
                REP25(DOTW)
                lds[OFF_ZBUF + j] = (a0 + a1) + (a2 + a3);
            }
            __syncthreads();
            if (j < H1_) {
                float zi = lds[OFF_ZBUF + j];
                float zf = lds[OFF_ZBUF + H1_ + j];
                float zg = lds[OFF_ZBUF + 2 * H1_ + j];
                float zo = lds[OFF_ZBUF + 3 * H1_ + j];
                float ig = sigm(zi);
                float fg = sigm(zf);
                float gg = fmaxf(zg, 0.0f);
                float og = sigm(zo);
                c1 = fg * c1 + ig * gg;
                float h = og * fmaxf(c1, 0.0f);
                lds[OFF_H1S + j] = h;
                lds[OFF_H1C + t * H1_ + j] = h;
            }
            __syncthreads();
        }

        // ---- A2: xp2[t][j] = b2[j] + h1_t . W2col_j  (dense) ----
        // xp2 aliases xs/xp1; A1's final barrier guarantees all reads done.
        {
            REP25(LDW2)
            const float bj = b2[j];
            for (int t = 0; t < TC; ++t) {
                const float4* hb4 = (const float4*)&lds[OFF_H1C + t * H1_];
                float a0 = bj, a1 = 0.f, a2 = 0.f, a3 = 0.f;
                REP25(DOTW)
                lds[OFF_XP2 + t * G2_ + j] = (a0 + a1) + (a2 + a3);
            }
            // swap in U2 column j: 32 float4 (rows 0..127)
            REP32(LDU2)
        }
        __syncthreads();   // xp2 complete

        // ---- B: layer-2 recurrence over the chunk ----
        for (int t = 0; t < TC; ++t) {
            {
                const float4* hb4 = (const float4*)&lds[OFF_H2S];
                float a0 = lds[OFF_XP2 + t * G2_ + j], a1 = 0.f, a2 = 0.f, a3 = 0.f;
                REP32(DOTW)
                lds[OFF_ZBUF + j] = (a0 + a1) + (a2 + a3);
            }
            __syncthreads();
            if (j < H2_) {
                float zi = lds[OFF_ZBUF + j];
                float zf = lds[OFF_ZBUF + H2_ + j];
                float zg = lds[OFF_ZBUF + 2 * H2_ + j];
                float zo = lds[OFF_ZBUF + 3 * H2_ + j];
                float ig = sigm(zi);
                float fg = sigm(zf);
                float gg = fmaxf(zg, 0.0f);
                float og = sigm(zo);
                c2 = fg * c2 + ig * gg;
                float h = og * fmaxf(c2, 0.0f);
                lds[OFF_H2S + j] = h;
            }
            __syncthreads();
        }
    }

    // ---- head: logits = h2_last @ Wd + bd ; softmax over 19 ----
    if (j < OUT_) {
        float acc = bd[j];
        #pragma unroll
        for (int k = 0; k < H2_; ++k) acc += lds[OFF_H2S + k] * Wd[k * OUT_ + j];
        lds[OFF_ZBUF + j] = acc;
    }
    __syncthreads();
    if (j < OUT_) {
        float m = -1e30f;
        for (int k = 0; k < OUT_; ++k) m = fmaxf(m, lds[OFF_ZBUF + k]);
        float s = 0.0f;
        for (int k = 0; k < OUT_; ++k) s += expf(lds[OFF_ZBUF + k] - m);
        out[b * OUT_ + j] = expf(lds[OFF_ZBUF + j] - m) / s;
    }
}

extern "C" void kernel_launch(void* const* d_in, const int* in_sizes, int n_in,
                              void* d_out, int out_size, void* d_ws, size_t ws_size,
                              hipStream_t stream) {
    const float* x  = (const float*)d_in[0];
    const float* W1 = (const float*)d_in[1];
    const float* U1 = (const float*)d_in[2];
    const float* b1 = (const float*)d_in[3];
    const float* W2 = (const float*)d_in[4];
    const float* U2 = (const float*)d_in[5];
    const float* b2 = (const float*)d_in[6];
    const float* Wd = (const float*)d_in[7];
    const float* bd = (const float*)d_in[8];
    float* out = (float*)d_out;

    hipLaunchKernelGGL(lstm_fused, dim3(B_), dim3(512), 0, stream,
                       x, W1, U1, b1, W2, U2, b2, Wd, bd, out);
}